// Round 15
// baseline (2323.326 us; speedup 1.0000x reference)
//
#include <hip/hip_runtime.h>
#include <stdint.h>

#define NTOK   4096
#define DMODEL 1024
#define HFF    4096
#define NEXP   8
#define BM     256
#define BK     64
#define MAX_MT 39            // true bound: 8192/256 + 7 = 39
#define KT1    16            // DMODEL/BK
#define KT2    64            // HFF/BK
#define PARTE  ((size_t)MAX_MT * 256 * DMODEL)   // u16 elems per split-K partial

typedef unsigned int   u32;
typedef unsigned short u16;
typedef u32   u32x4  __attribute__((ext_vector_type(4)));
typedef short s16x8  __attribute__((ext_vector_type(8)));
typedef float f32x4  __attribute__((ext_vector_type(4)));

__device__ __forceinline__ u16 f2bf(float f) {
  u32 u = __builtin_bit_cast(u32, f);
  return (u16)((u + 0x7FFFu + ((u >> 16) & 1u)) >> 16);   // RNE, finite inputs
}
__device__ __forceinline__ float bf2f(u32 lo16) {
  return __builtin_bit_cast(float, lo16 << 16);
}

// async global->LDS, 16B/lane; LDS dest = wave-uniform base + lane*16
__device__ __forceinline__ void gld_lds16(const void* g, void* l) {
  __builtin_amdgcn_global_load_lds((const __attribute__((address_space(1))) void*)g,
                                   (__attribute__((address_space(3))) void*)l, 16, 0, 0);
}

// ---- fragment-image format (per 64k x 256n tile, 2048 u32x4 = 32KB) ----------
// entry g*64+l: g=(k>>5)*16+(n>>4), l=((k>>3)&3)*16+(n&15), elem j=k&7 -> T[k][n]
// Half k32 of tile t lives at image offset (2*t + k32)*1024 -- linear in halves.

// ------- W [K][N] fp32 -> fragment image tile (256 threads) --------------------
__device__ void prearr_dev(const float* __restrict__ W, u32x4* __restrict__ Bp,
                           int K, int N, int NT, int KT, int tile, u32x4* img4) {
  int kt  = tile % KT; int rem = tile / KT;
  int nt  = rem % NT;  int e   = rem / NT;
  u32* img = (u32*)img4;
  const int tid = threadIdx.x;
  const float* src = W + ((size_t)e * K + (size_t)kt * BK) * N + (size_t)nt * 256;
  const int c4 = (tid & 63) * 4;     // n: 0,4,...,252
  const int k0 = (tid >> 6) * 2;     // 0,2,4,6
#pragma unroll
  for (int p = 0; p < 8; ++p) {
    const int k = k0 + p * 8;        // even
    float4 v0 = *(const float4*)(src + (size_t)k * N + c4);
    float4 v1 = *(const float4*)(src + (size_t)(k + 1) * N + c4);
    u32 w[4] = { (u32)f2bf(v0.x) | ((u32)f2bf(v1.x) << 16),
                 (u32)f2bf(v0.y) | ((u32)f2bf(v1.y) << 16),
                 (u32)f2bf(v0.z) | ((u32)f2bf(v1.z) << 16),
                 (u32)f2bf(v0.w) | ((u32)f2bf(v1.w) << 16) };
#pragma unroll
    for (int q = 0; q < 4; ++q) {
      const int n = c4 + q;
      const int ent = ((k >> 5) * 16 + (n >> 4)) * 64 + ((k >> 3) & 3) * 16 + (n & 15);
      img[ent * 4 + ((k & 7) >> 1)] = w[q];
    }
  }
  __syncthreads();
  u32x4* outp = Bp + (size_t)tile * 2048;
#pragma unroll
  for (int c = 0; c < 8; ++c) outp[c * 256 + tid] = img4[c * 256 + tid];
}

// ---- gather tokens (fp32 x) -> A fragment image tile (256 threads) ------------
__device__ void arrange_dev(const float* __restrict__ x, const int* __restrict__ tok_of_slot,
                            const int* __restrict__ mtile_e, u32x4* __restrict__ Ap,
                            int j, u32x4* img) {
  const int mt = j >> 4, kt = j & 15;
  if (mtile_e[mt] < 0) return;
  u16* imgu = (u16*)img;
  const int tid = threadIdx.x;
  const int lane16 = tid & 15, rp = tid >> 4;
#pragma unroll
  for (int p = 0; p < 16; ++p) {
    const int row = rp + p * 16;
    const int tok = tok_of_slot[mt * BM + row];
    float4 v = *(const float4*)(x + (size_t)tok * DMODEL + kt * BK + lane16 * 4);
    const int g = (lane16 >> 3) * 16 + (row >> 4);
    const int l = ((lane16 >> 1) & 3) * 16 + (row & 15);
    u32* dst = (u32*)(imgu + (size_t)(g * 64 + l) * 8 + (lane16 & 1) * 4);
    dst[0] = (u32)f2bf(v.x) | ((u32)f2bf(v.y) << 16);
    dst[1] = (u32)f2bf(v.z) | ((u32)f2bf(v.w) << 16);
  }
  __syncthreads();
  u32x4* outp = Ap + (size_t)j * 2048;
#pragma unroll
  for (int c = 0; c < 8; ++c) outp[c * 256 + tid] = img[c * 256 + tid];
}

// ---- merged prep: preW1 (2048) | preW2 (2048) | arrange_a (624) ----------------
__global__ __launch_bounds__(256) void k_prep(
    const float* __restrict__ W1, const float* __restrict__ W2,
    u32x4* __restrict__ Bp1, u32x4* __restrict__ Bp2,
    const float* __restrict__ x, const int* __restrict__ tok_of_slot,
    const int* __restrict__ mtile_e, u32x4* __restrict__ Ap1) {
  __shared__ u32x4 img[2048];        // 32KB
  const int bid = blockIdx.x;
  if (bid < 2048)       prearr_dev(W1, Bp1, DMODEL, HFF, 16, 16, bid, img);
  else if (bid < 4096)  prearr_dev(W2, Bp2, HFF, DMODEL, 4, 64, bid - 2048, img);
  else                  arrange_dev(x, tok_of_slot, mtile_e, Ap1, bid - 4096, img);
}

// ---------------- gating: logits, top-2, softmax(2), counts ----------------
__global__ void k_gating(const float* __restrict__ x, const float* __restrict__ Wg,
                         const float* __restrict__ bg, int* __restrict__ top_idx,
                         float* __restrict__ top_w, int* __restrict__ counts) {
  int t = blockIdx.x, tid = threadIdx.x;
  float acc[NEXP];
#pragma unroll
  for (int e = 0; e < NEXP; ++e) acc[e] = 0.f;
  const float* xr = x + (size_t)t * DMODEL;
  for (int d = tid; d < DMODEL; d += 256) {
    float xv = xr[d];
    const float4* wg = (const float4*)(Wg + d * NEXP);
    float4 a = wg[0], b = wg[1];
    acc[0] += xv * a.x; acc[1] += xv * a.y; acc[2] += xv * a.z; acc[3] += xv * a.w;
    acc[4] += xv * b.x; acc[5] += xv * b.y; acc[6] += xv * b.z; acc[7] += xv * b.w;
  }
#pragma unroll
  for (int e = 0; e < NEXP; ++e)
#pragma unroll
    for (int off = 32; off; off >>= 1) acc[e] += __shfl_down(acc[e], off);
  __shared__ float red[4][NEXP];
  int w = tid >> 6;
  if ((tid & 63) == 0)
    for (int e = 0; e < NEXP; ++e) red[w][e] = acc[e];
  __syncthreads();
  if (tid == 0) {
    float v0 = -1e30f, v1 = -1e30f; int i0 = 0, i1 = 0;
    for (int e = 0; e < NEXP; ++e) {
      float l = red[0][e] + red[1][e] + red[2][e] + red[3][e] + bg[e];
      if (l > v0)      { v1 = v0; i1 = i0; v0 = l; i0 = e; }
      else if (l > v1) { v1 = l; i1 = e; }
    }
    float e1 = expf(v1 - v0);
    float w0 = 1.f / (1.f + e1);
    top_idx[2 * t] = i0; top_idx[2 * t + 1] = i1;
    top_w[2 * t] = w0;   top_w[2 * t + 1] = e1 * w0;
    atomicAdd(&counts[i0], 1); atomicAdd(&counts[i1], 1);
  }
}

// -------- scatter + (merged) offsets/tile-map: each thread derives prefix ------
__global__ void k_scatter(const int* __restrict__ counts, int* __restrict__ mtile_e,
                          int* __restrict__ cursor, const int* __restrict__ top_idx,
                          int* __restrict__ tok_of_slot, int* __restrict__ token_slot) {
  int poff[NEXP];
  {
    int off = 0;
#pragma unroll
    for (int e = 0; e < NEXP; ++e) {
      poff[e] = off;
      off += (counts[e] + BM - 1) / BM * BM;
    }
  }
  if (blockIdx.x == 0 && threadIdx.x == 0) {
    int nm = 0;
    for (int e = 0; e < NEXP; ++e) {
      int ntl = (counts[e] + BM - 1) / BM;
      for (int lt = 0; lt < ntl; ++lt) mtile_e[nm++] = e;
    }
    for (; nm < MAX_MT; ++nm) mtile_e[nm] = -1;
  }
  int t = blockIdx.x * 256 + threadIdx.x;
  if (t >= NTOK) return;
  for (int k = 0; k < 2; ++k) {
    int e = top_idx[2 * t + k];
    int p = atomicAdd(&cursor[e], 1);
    int slot = poff[e] + p;
    tok_of_slot[slot] = t;
    token_slot[2 * t + k] = slot;
  }
}

// ---------------- grouped GEMM, 2-deep ring / 2 blocks per CU -------------------
// 256x256xBK64 tile, 512 threads / 8 waves (2M x 4N), acc[8][4] per wave.
// 2-deep half-K-slab ring per operand (64KB LDS -> 2 blocks/CU co-resident;
// cross-block overlap hides the per-half barrier+vmcnt stalls, m97/m114 style).
// Per half H: counted vmcnt(4) (slab H landed, H+1 in flight) -> barrier ->
// ds_read + 32 MFMA @prio1 -> barrier (all reads done) -> stage(H+2) issue.
// MODE 1: full K (NH=32), GELU+bias, writes h as GEMM2 A-images (2-pass 64KB).
// MODE 0: split-K=4 (kh from grid, NH=32 of 128), bf16 partial via swizzled-LDS
//         (2-pass) -> coalesced u32x4 row writes; bias deferred to combine.
template <int MODE>
__global__ __launch_bounds__(512, 4) void k_gemm(
    const u32x4* __restrict__ Ap, int halvesK,
    const u32x4* __restrict__ Bp,
    const float* __restrict__ bias, int Nfull, int NT,
    const int* __restrict__ mtile_e, void* __restrict__ outv) {
  const u32 nwg  = gridDim.x;
  const u32 orig = blockIdx.x;
  const u32 gsw  = (orig & 7u) * (nwg >> 3) + (orig >> 3);  // XCD chunks, mt-fastest
  const int mt = (int)(gsw % MAX_MT);
  const u32 q  = gsw / MAX_MT;
  int nt, kh, Hbase, NH;
  if (MODE) { nt = (int)q; kh = 0; Hbase = 0; NH = halvesK; }
  else      { nt = (int)(q & 3); kh = (int)(q >> 2);
              NH = halvesK / 4; Hbase = kh * NH; }
  const int e = mtile_e[mt];
  if (e < 0) return;

  __shared__ u32x4 LB[4096];          // 64KB; A ring [0,2048), B ring [2048,4096)
  u32x4* AsR = LB;
  u32x4* BsR = LB + 2048;

  const int tid  = threadIdx.x;
  const int lane = tid & 63;
  const int wv   = tid >> 6;          // 0..7
  const int wm   = wv >> 2;           // 0..1
  const int wn   = wv & 3;            // 0..3

  const u32x4* abase = Ap + ((size_t)mt * halvesK + Hbase) * 1024;
  const u32x4* bbase = Bp + ((size_t)(e * NT + nt) * halvesK + Hbase) * 1024;

  auto stageAB = [&](int Hs) {
    const int s = Hs & 1;
    const u32x4* sa = abase + (size_t)Hs * 1024;
    const u32x4* sb = bbase + (size_t)Hs * 1024;
    gld_lds16(sa + (wv * 2 + 0) * 64 + lane, &AsR[s * 1024 + (wv * 2 + 0) * 64]);
    gld_lds16(sa + (wv * 2 + 1) * 64 + lane, &AsR[s * 1024 + (wv * 2 + 1) * 64]);
    gld_lds16(sb + (wv * 2 + 0) * 64 + lane, &BsR[s * 1024 + (wv * 2 + 0) * 64]);
    gld_lds16(sb + (wv * 2 + 1) * 64 + lane, &BsR[s * 1024 + (wv * 2 + 1) * 64]);
  };

  f32x4 acc[8][4] = {};

  stageAB(0); stageAB(1);             // 8 loads in flight

  for (int H = 0; H < NH; ++H) {
    if (H + 1 < NH) asm volatile("s_waitcnt vmcnt(4)" ::: "memory");
    else            asm volatile("s_waitcnt vmcnt(0)" ::: "memory");
    __builtin_amdgcn_sched_barrier(0);
    __builtin_amdgcn_s_barrier();     // slab H complete in all waves
    __builtin_amdgcn_sched_barrier(0);
    const u32x4* Ah = AsR + (H & 1) * 1024;
    const u32x4* Bh = BsR + (H & 1) * 1024;
    s16x8 a[4], b[4];
#pragma unroll
    for (int ni = 0; ni < 4; ++ni)
      b[ni] = __builtin_bit_cast(s16x8, Bh[(wn * 4 + ni) * 64 + lane]);
#pragma unroll
    for (int mi = 0; mi < 4; ++mi)
      a[mi] = __builtin_bit_cast(s16x8, Ah[(wm * 8 + mi) * 64 + lane]);
    __builtin_amdgcn_s_setprio(1);
#pragma unroll
    for (int mi = 0; mi < 4; ++mi)
#pragma unroll
      for (int ni = 0; ni < 4; ++ni)
        acc[mi][ni] = __builtin_amdgcn_mfma_f32_16x16x32_bf16(a[mi], b[ni], acc[mi][ni], 0, 0, 0);
    __builtin_amdgcn_s_setprio(0);
#pragma unroll
    for (int mi = 0; mi < 4; ++mi)
      a[mi] = __builtin_bit_cast(s16x8, Ah[(wm * 8 + 4 + mi) * 64 + lane]);
    __builtin_amdgcn_s_setprio(1);
#pragma unroll
    for (int mi = 0; mi < 4; ++mi)
#pragma unroll
      for (int ni = 0; ni < 4; ++ni)
        acc[4 + mi][ni] = __builtin_amdgcn_mfma_f32_16x16x32_bf16(a[mi], b[ni], acc[4 + mi][ni], 0, 0, 0);
    __builtin_amdgcn_s_setprio(0);
    __builtin_amdgcn_sched_barrier(0);
    __builtin_amdgcn_s_barrier();     // all reads of slab H done everywhere
    __builtin_amdgcn_sched_barrier(0);
    if (H + 2 < NH) stageAB(H + 2);   // safe: ring slot (H&1) free now
  }

  __syncthreads();                    // LDS free for epilogue

  const int rbase = ((lane >> 4) << 2);
  const int c16 = lane & 15;
  if (MODE) {
    // ---- GELU+bias; 2-pass image staging (2 x 32KB h-tiles per pass)
    u16* cimg = (u16*)LB;
    float bv[4];
#pragma unroll
    for (int ni = 0; ni < 4; ++ni)
      bv[ni] = bias[(size_t)e * Nfull + nt * 256 + wn * 64 + ni * 16 + c16];
#pragma unroll
    for (int p = 0; p < 2; ++p) {
      if ((wn >> 1) == p) {
#pragma unroll
        for (int mi = 0; mi < 8; ++mi)
#pragma unroll
          for (int ni = 0; ni < 4; ++ni)
#pragma unroll
            for (int r = 0; r < 4; ++r) {
              const int row = wm * 128 + mi * 16 + rbase + r;
              const int cl = (wn & 1) * 64 + ni * 16 + c16;   // 0..127
              float v = acc[mi][ni][r] + bv[ni];
              v = 0.5f * v * (1.0f + erff(v * 0.70710678118654752f));
              const int k = cl & 63;
              const int ent = (cl >> 6) * 2048
                            + ((k >> 5) * 16 + (row >> 4)) * 64
                            + ((k >> 3) & 3) * 16 + (row & 15);
              cimg[ent * 8 + (k & 7)] = f2bf(v);
            }
      }
      __syncthreads();
      u32x4* outp = (u32x4*)outv + ((size_t)mt * KT2 + nt * 4 + p * 2) * 2048;
#pragma unroll
      for (int c = 0; c < 8; ++c) outp[c * 512 + tid] = LB[c * 512 + tid];
      __syncthreads();
    }
  } else {
    // ---- bf16 split-K partial via swizzled LDS (u16[256][128], 2 passes)
    u16* cimg = (u16*)LB;
#pragma unroll
    for (int p = 0; p < 2; ++p) {
      if ((wn >> 1) == p) {
#pragma unroll
        for (int mi = 0; mi < 8; ++mi)
#pragma unroll
          for (int ni = 0; ni < 4; ++ni)
#pragma unroll
            for (int r = 0; r < 4; ++r) {
              const int row = wm * 128 + mi * 16 + rbase + r;
              const int cl = (wn & 1) * 64 + ni * 16 + c16;   // 0..127
              const int ch = cl >> 3;                          // 0..15
              cimg[row * 128 + ((ch ^ (row & 15)) << 3) + (cl & 7)] = f2bf(acc[mi][ni][r]);
            }
      }
      __syncthreads();
      u16* o = (u16*)outv + (size_t)kh * PARTE + (size_t)mt * 256 * DMODEL
             + nt * 256 + p * 128;
      // full tile per pass = 256 rows x 16 u32x4-chunks = 4096 u32x4 (FIX: c<8)
#pragma unroll
      for (int c = 0; c < 8; ++c) {
        const int cid = c * 512 + tid;    // 0..4095
        const int row = cid >> 4, ch = cid & 15;
        *(u32x4*)&o[(size_t)row * DMODEL + ch * 8] = LB[row * 16 + (ch ^ (row & 15))];
      }
      __syncthreads();
    }
  }
}

// -------- combine: sum 4 bf16 partials + bias, top-2 weight, residual, LN ------
__global__ void k_combine_ln(const float* __restrict__ x, const u16* __restrict__ part,
                             const int* __restrict__ token_slot, const int* __restrict__ top_idx,
                             const float* __restrict__ top_w, const float* __restrict__ b2,
                             const float* __restrict__ gamma, const float* __restrict__ beta,
                             float* __restrict__ out) {
  int t = blockIdx.x, tid = threadIdx.x;
  int s0 = token_slot[2 * t], s1 = token_slot[2 * t + 1];
  int e0 = top_idx[2 * t],   e1 = top_idx[2 * t + 1];
  float w0 = top_w[2 * t], w1 = top_w[2 * t + 1];
  float4 xv = ((const float4*)(x + (size_t)t * DMODEL))[tid];
  float y0[4] = {}, y1[4] = {};
  const size_t i0 = (size_t)s0 * DMODEL + tid * 4;
  const size_t i1 = (size_t)s1 * DMODEL + tid * 4;
#pragma unroll
  for (int kh = 0; kh < 4; ++kh) {
    uint2 a = *(const uint2*)(part + kh * PARTE + i0);
    uint2 b = *(const uint2*)(part + kh * PARTE + i1);
    y0[0] += bf2f(a.x & 0xffffu); y0[1] += bf2f(a.x >> 16);
    y0[2] += bf2f(a.y & 0xffffu); y0[3] += bf2f(a.y >> 16);
    y1[0] += bf2f(b.x & 0xffffu); y1[1] += bf2f(b.x >> 16);
    y1[2] += bf2f(b.y & 0xffffu); y1[3] += bf2f(b.y >> 16);
  }
  float4 bb0 = ((const float4*)(b2 + (size_t)e0 * DMODEL))[tid];
  float4 bb1 = ((const float4*)(b2 + (size_t)e1 * DMODEL))[tid];
  float r0 = xv.x + w0 * (y0[0] + bb0.x) + w1 * (y1[0] + bb1.x);
  float r1 = xv.y + w0 * (y0[1] + bb0.y) + w1 * (y1[1] + bb1.y);
  float r2 = xv.z + w0 * (y0[2] + bb0.z) + w1 * (y1[2] + bb1.z);
  float r3 = xv.w + w0 * (y0[3] + bb0.w) + w1 * (y1[3] + bb1.w);
  float s  = r0 + r1 + r2 + r3;
  float sq = r0 * r0 + r1 * r1 + r2 * r2 + r3 * r3;
#pragma unroll
  for (int off = 32; off; off >>= 1) { s += __shfl_down(s, off); sq += __shfl_down(sq, off); }
  __shared__ float rs[4], rq[4];
  __shared__ float mu_s, rsig_s;
  int w = tid >> 6;
  if ((tid & 63) == 0) { rs[w] = s; rq[w] = sq; }
  __syncthreads();
  if (tid == 0) {
    float S = rs[0] + rs[1] + rs[2] + rs[3];
    float Q = rq[0] + rq[1] + rq[2] + rq[3];
    float mu  = S * (1.0f / DMODEL);
    float var = Q * (1.0f / DMODEL) - mu * mu;
    mu_s = mu; rsig_s = rsqrtf(var + 1e-5f);
  }
  __syncthreads();
  float mu = mu_s, rsig = rsig_s;
  float4 gv = ((const float4*)gamma)[tid];
  float4 bv = ((const float4*)beta)[tid];
  float4 o;
  o.x = (r0 - mu) * rsig * gv.x + bv.x;
  o.y = (r1 - mu) * rsig * gv.y + bv.y;
  o.z = (r2 - mu) * rsig * gv.z + bv.z;
  o.w = (r3 - mu) * rsig * gv.w + bv.w;
  ((float4*)(out + (size_t)t * DMODEL))[tid] = o;
}

// ---------------- launch ----------------
extern "C" void kernel_launch(void* const* d_in, const int* in_sizes, int n_in,
                              void* d_out, int out_size, void* d_ws, size_t ws_size,
                              hipStream_t stream) {
  const float* x     = (const float*)d_in[0];
  const float* Wg    = (const float*)d_in[1];
  const float* bg    = (const float*)d_in[2];
  const float* W1    = (const float*)d_in[3];
  const float* b1    = (const float*)d_in[4];
  const float* W2    = (const float*)d_in[5];
  const float* b2    = (const float*)d_in[6];
  const float* gamma = (const float*)d_in[7];
  const float* beta  = (const float*)d_in[8];
  float* out = (float*)d_out;

  // ws ~236.6MB: [Ap1 19.5MiB | Bp1 64MiB][Bp2 64MiB][hImg 78MiB][meta]
  // part (78MiB, 4 bf16 partials) aliases [Ap1|Bp1] (dead after GEMM1).
  char* ws = (char*)d_ws;
  const size_t szAp1 = (size_t)MAX_MT * KT1 * 2048 * 16;         // 19.5 MiB
  const size_t szBp  = (size_t)NEXP * DMODEL * HFF * 2;          // 64 MiB
  u32x4* Ap1  = (u32x4*)ws;
  u32x4* Bp1  = (u32x4*)(ws + szAp1);
  u16*   part = (u16*)ws;                                        // alias
  u32x4* Bp2  = (u32x4*)(ws + szAp1 + szBp);
  char* p = ws + szAp1 + 2 * szBp;
  u16*   hImg = (u16*)p;  p += (size_t)MAX_MT * KT2 * 2048 * 16; // 78 MiB
  int*   meta = (int*)p;
  int*   counts      = meta;
  int*   cursor      = counts + 8;
  int*   tok_of_slot = cursor + 8;
  int*   mtile_e     = tok_of_slot + MAX_MT * BM;
  int*   token_slot  = mtile_e + MAX_MT + 1;
  int*   top_idx     = token_slot + 2 * NTOK;
  float* top_w       = (float*)(top_idx + 2 * NTOK);
  (void)ws_size; (void)in_sizes; (void)n_in; (void)out_size;

  hipMemsetAsync(meta, 0, (size_t)(16 + MAX_MT * BM) * 4, stream);

  k_gating<<<NTOK, 256, 0, stream>>>(x, Wg, bg, top_idx, top_w, counts);
  k_scatter<<<NTOK / 256, 256, 0, stream>>>(counts, mtile_e, cursor, top_idx,
                                            tok_of_slot, token_slot);

  // merged prep: preW1 (2048) + preW2 (2048) + arrange_a (624) = 4720 blocks
  k_prep<<<2048 + 2048 + MAX_MT * KT1, 256, 0, stream>>>(
      W1, W2, Bp1, Bp2, x, tok_of_slot, mtile_e, Ap1);

  // GEMM1: 16 nt x 39 mt = 624 blocks (8*78); GELU; writes h as GEMM2 A-images
  k_gemm<1><<<(HFF / 256) * MAX_MT, 512, 0, stream>>>(
      Ap1, 2 * KT1, Bp1, b1, HFF, HFF / 256, mtile_e, (void*)hImg);

  // GEMM2: 4 nt x 39 mt x 4 kh = 624 blocks (8*78); bf16 partials -> part
  k_gemm<0><<<(DMODEL / 256) * MAX_MT * 4, 512, 0, stream>>>(
      (const u32x4*)hImg, 2 * KT2, Bp2, nullptr, DMODEL, DMODEL / 256,
      mtile_e, (void*)part);

  k_combine_ln<<<NTOK, 256, 0, stream>>>(x, part, token_slot, top_idx, top_w,
                                         b2, gamma, beta, out);
}

// Round 16
// 440.443 us; speedup vs baseline: 5.2750x; 5.2750x over previous
//
#include <hip/hip_runtime.h>
#include <stdint.h>

#define NTOK   4096
#define DMODEL 1024
#define HFF    4096
#define NEXP   8
#define BM     256
#define BK     64
#define MAX_MT 39            // live bound: 8192/256 + 7 = 39
#define MT_PAD 40            // grid padding so nwg % 8 == 0
#define KT1    16            // DMODEL/BK
#define KT2    64            // HFF/BK
#define NWG1   640           // 16 nt x 40 mt
#define NWG2   160           // 4 nt x 40 mt

typedef unsigned int   u32;
typedef unsigned short u16;
typedef u32   u32x4  __attribute__((ext_vector_type(4)));
typedef short s16x8  __attribute__((ext_vector_type(8)));
typedef float f32x4  __attribute__((ext_vector_type(4)));

__device__ __forceinline__ u16 f2bf(float f) {
  u32 u = __builtin_bit_cast(u32, f);
  return (u16)((u + 0x7FFFu + ((u >> 16) & 1u)) >> 16);   // RNE, finite inputs
}
__device__ __forceinline__ float bf2f(u32 lo16) {
  return __builtin_bit_cast(float, lo16 << 16);
}

// async global->LDS, 16B/lane; LDS dest = wave-uniform base + lane*16
__device__ __forceinline__ void gld_lds16(const void* g, void* l) {
  __builtin_amdgcn_global_load_lds((const __attribute__((address_space(1))) void*)g,
                                   (__attribute__((address_space(3))) void*)l, 16, 0, 0);
}

// ---- fragment-image format (per 64k x 256n tile, 2048 u32x4 = 32KB) ----------
// entry g*64+l: g=(k>>5)*16+(n>>4), l=((k>>3)&3)*16+(n&15), elem j=k&7 -> T[k][n]
// Half k32 of tile t lives at image offset (2*t + k32)*1024 -- linear in halves.

// ------- W [K][N] fp32 -> fragment image tile (256 threads) --------------------
__device__ void prearr_dev(const float* __restrict__ W, u32x4* __restrict__ Bp,
                           int K, int N, int NT, int KT, int tile, u32x4* img4) {
  int kt  = tile % KT; int rem = tile / KT;
  int nt  = rem % NT;  int e   = rem / NT;
  u32* img = (u32*)img4;
  const int tid = threadIdx.x;
  const float* src = W + ((size_t)e * K + (size_t)kt * BK) * N + (size_t)nt * 256;
  const int c4 = (tid & 63) * 4;
  const int k0 = (tid >> 6) * 2;     // 0,2,4,6
#pragma unroll
  for (int p = 0; p < 8; ++p) {
    const int k = k0 + p * 8;        // even
    float4 v0 = *(const float4*)(src + (size_t)k * N + c4);
    float4 v1 = *(const float4*)(src + (size_t)(k + 1) * N + c4);
    u32 w[4] = { (u32)f2bf(v0.x) | ((u32)f2bf(v1.x) << 16),
                 (u32)f2bf(v0.y) | ((u32)f2bf(v1.y) << 16),
                 (u32)f2bf(v0.z) | ((u32)f2bf(v1.z) << 16),
                 (u32)f2bf(v0.w) | ((u32)f2bf(v1.w) << 16) };
#pragma unroll
    for (int q = 0; q < 4; ++q) {
      const int n = c4 + q;
      const int ent = ((k >> 5) * 16 + (n >> 4)) * 64 + ((k >> 3) & 3) * 16 + (n & 15);
      img[ent * 4 + ((k & 7) >> 1)] = w[q];
    }
  }
  __syncthreads();
  u32x4* outp = Bp + (size_t)tile * 2048;
#pragma unroll
  for (int c = 0; c < 8; ++c) outp[c * 256 + tid] = img4[c * 256 + tid];
}

// ------- 512-thread variant (verified in R12) for backfill inside GEMM1 --------
__device__ void prearr512(const float* __restrict__ W, u32x4* __restrict__ Bp,
                          int K, int N, int NT, int KT, int tile, u32x4* LB) {
  int kt  = tile % KT; int rem = tile / KT;
  int nt  = rem % NT;  int e   = rem / NT;
  u32* img = (u32*)LB;
  const int tid = threadIdx.x;
  const float* src = W + ((size_t)e * K + (size_t)kt * BK) * N + (size_t)nt * 256;
  const int c4 = (tid & 63) * 4;
  const int k0 = (tid >> 6) * 2;     // 0..14 even
#pragma unroll
  for (int p = 0; p < 4; ++p) {
    const int k = k0 + p * 16;       // even, covers 0..62
    float4 v0 = *(const float4*)(src + (size_t)k * N + c4);
    float4 v1 = *(const float4*)(src + (size_t)(k + 1) * N + c4);
    u32 w[4] = { (u32)f2bf(v0.x) | ((u32)f2bf(v1.x) << 16),
                 (u32)f2bf(v0.y) | ((u32)f2bf(v1.y) << 16),
                 (u32)f2bf(v0.z) | ((u32)f2bf(v1.z) << 16),
                 (u32)f2bf(v0.w) | ((u32)f2bf(v1.w) << 16) };
#pragma unroll
    for (int q = 0; q < 4; ++q) {
      const int n = c4 + q;
      const int ent = ((k >> 5) * 16 + (n >> 4)) * 64 + ((k >> 3) & 3) * 16 + (n & 15);
      img[ent * 4 + ((k & 7) >> 1)] = w[q];
    }
  }
  __syncthreads();
  u32x4* outp = Bp + (size_t)tile * 2048;
#pragma unroll
  for (int c = 0; c < 4; ++c) outp[c * 512 + tid] = LB[c * 512 + tid];
}

// ---- gather tokens (fp32 x) -> A fragment image tile (256 threads) ------------
__device__ void arrange_dev(const float* __restrict__ x, const int* __restrict__ tok_of_slot,
                            const int* __restrict__ mtile_e, u32x4* __restrict__ Ap,
                            int j, u32x4* img) {
  const int mt = j >> 4, kt = j & 15;
  if (mtile_e[mt] < 0) return;
  u16* imgu = (u16*)img;
  const int tid = threadIdx.x;
  const int lane16 = tid & 15, rp = tid >> 4;
#pragma unroll
  for (int p = 0; p < 16; ++p) {
    const int row = rp + p * 16;
    const int tok = tok_of_slot[mt * BM + row];
    float4 v = *(const float4*)(x + (size_t)tok * DMODEL + kt * BK + lane16 * 4);
    const int g = (lane16 >> 3) * 16 + (row >> 4);
    const int l = ((lane16 >> 1) & 3) * 16 + (row & 15);
    u32* dst = (u32*)(imgu + (size_t)(g * 64 + l) * 8 + (lane16 & 1) * 4);
    dst[0] = (u32)f2bf(v.x) | ((u32)f2bf(v.y) << 16);
    dst[1] = (u32)f2bf(v.z) | ((u32)f2bf(v.w) << 16);
  }
  __syncthreads();
  u32x4* outp = Ap + (size_t)j * 2048;
#pragma unroll
  for (int c = 0; c < 8; ++c) outp[c * 256 + tid] = img[c * 256 + tid];
}

// ---- prep: preW1 (2048) | arrange_a (624) --------------------------------------
__global__ __launch_bounds__(256) void k_prep(
    const float* __restrict__ W1, u32x4* __restrict__ Bp1,
    const float* __restrict__ x, const int* __restrict__ tok_of_slot,
    const int* __restrict__ mtile_e, u32x4* __restrict__ Ap1) {
  __shared__ u32x4 img[2048];        // 32KB
  const int bid = blockIdx.x;
  if (bid < 2048) prearr_dev(W1, Bp1, DMODEL, HFF, 16, 16, bid, img);
  else            arrange_dev(x, tok_of_slot, mtile_e, Ap1, bid - 2048, img);
}

// ---------------- gating: logits, top-2, softmax(2), counts ----------------
__global__ void k_gating(const float* __restrict__ x, const float* __restrict__ Wg,
                         const float* __restrict__ bg, int* __restrict__ top_idx,
                         float* __restrict__ top_w, int* __restrict__ counts) {
  int t = blockIdx.x, tid = threadIdx.x;
  float acc[NEXP];
#pragma unroll
  for (int e = 0; e < NEXP; ++e) acc[e] = 0.f;
  const float* xr = x + (size_t)t * DMODEL;
  for (int d = tid; d < DMODEL; d += 256) {
    float xv = xr[d];
    const float4* wg = (const float4*)(Wg + d * NEXP);
    float4 a = wg[0], b = wg[1];
    acc[0] += xv * a.x; acc[1] += xv * a.y; acc[2] += xv * a.z; acc[3] += xv * a.w;
    acc[4] += xv * b.x; acc[5] += xv * b.y; acc[6] += xv * b.z; acc[7] += xv * b.w;
  }
#pragma unroll
  for (int e = 0; e < NEXP; ++e)
#pragma unroll
    for (int off = 32; off; off >>= 1) acc[e] += __shfl_down(acc[e], off);
  __shared__ float red[4][NEXP];
  int w = tid >> 6;
  if ((tid & 63) == 0)
    for (int e = 0; e < NEXP; ++e) red[w][e] = acc[e];
  __syncthreads();
  if (tid == 0) {
    float v0 = -1e30f, v1 = -1e30f; int i0 = 0, i1 = 0;
    for (int e = 0; e < NEXP; ++e) {
      float l = red[0][e] + red[1][e] + red[2][e] + red[3][e] + bg[e];
      if (l > v0)      { v1 = v0; i1 = i0; v0 = l; i0 = e; }
      else if (l > v1) { v1 = l; i1 = e; }
    }
    float e1 = expf(v1 - v0);
    float w0 = 1.f / (1.f + e1);
    top_idx[2 * t] = i0; top_idx[2 * t + 1] = i1;
    top_w[2 * t] = w0;   top_w[2 * t + 1] = e1 * w0;
    atomicAdd(&counts[i0], 1); atomicAdd(&counts[i1], 1);
  }
}

// -------- scatter + merged offsets/tile-map --------------------------------------
__global__ void k_scatter(const int* __restrict__ counts, int* __restrict__ mtile_e,
                          int* __restrict__ cursor, const int* __restrict__ top_idx,
                          int* __restrict__ tok_of_slot, int* __restrict__ token_slot) {
  int poff[NEXP];
  {
    int off = 0;
#pragma unroll
    for (int e = 0; e < NEXP; ++e) {
      poff[e] = off;
      off += (counts[e] + BM - 1) / BM * BM;
    }
  }
  if (blockIdx.x == 0 && threadIdx.x == 0) {
    int nm = 0;
    for (int e = 0; e < NEXP; ++e) {
      int ntl = (counts[e] + BM - 1) / BM;
      for (int lt = 0; lt < ntl; ++lt) mtile_e[nm++] = e;
    }
    for (; nm < MT_PAD; ++nm) mtile_e[nm] = -1;
  }
  int t = blockIdx.x * 256 + threadIdx.x;
  if (t >= NTOK) return;
  for (int k = 0; k < 2; ++k) {
    int e = top_idx[2 * t + k];
    int p = atomicAdd(&cursor[e], 1);
    int slot = poff[e] + p;
    tok_of_slot[slot] = t;
    token_slot[2 * t + k] = slot;
  }
}

// ---------------- grouped GEMM, R8 ring schedule (measured best) ----------------
// 256x256xBK64 tile, 512 threads / 8 waves (2M x 4N), acc[8][4] per wave.
// 4-deep half-K-slab ring per operand (128KB LDS, 1 block/CU, VGPR cap 256).
// Per half H: counted vmcnt (8/4/0 tail) -> raw s_barrier ->
// {stageA(H+3) | ds_read | 16 MFMA @prio1} -> {stageB(H+3) | ds_read | 16 MFMA}.
// MODE 1: grid NWG1+2048; blocks >= NWG1 run preW2 prearrange (tail backfill).
//         GEMM path: GELU+bias, writes h as GEMM2 A-images.
// MODE 0: grid NWG2; bias + bf16 y, swizzled-LDS staging -> coalesced rows.
template <int MODE>
__global__ __launch_bounds__(512, 2) void k_gemm(
    const u32x4* __restrict__ Ap, int halvesK,
    const u32x4* __restrict__ Bp,
    const float* __restrict__ bias, int Nfull, int NT,
    const int* __restrict__ mtile_e, void* __restrict__ outv,
    const float* __restrict__ Wsrc2, u32x4* __restrict__ Bp2out, int nwgGemm) {
  __shared__ u32x4 LB[8192];          // 128KB; A ring [0,4096), B ring [4096,8192)

  const u32 orig = blockIdx.x;
  if (MODE == 1 && (int)orig >= nwgGemm) {          // preW2 backfill block
    prearr512(Wsrc2, Bp2out, HFF, DMODEL, 4, 64, (int)orig - nwgGemm, LB);
    return;
  }
  const u32 nw   = (u32)nwgGemm;
  const u32 gsw  = (orig & 7u) * (nw >> 3) + (orig >> 3);  // XCD chunks, mt-fastest
  const int mt = (int)(gsw % MT_PAD);
  const int nt = (int)(gsw / MT_PAD);
  const int e = mtile_e[mt];
  if (e < 0) return;

  u32x4* AsR = LB;
  u32x4* BsR = LB + 4096;

  const int tid  = threadIdx.x;
  const int lane = tid & 63;
  const int wv   = tid >> 6;          // 0..7
  const int wm   = wv >> 2;           // 0..1
  const int wn   = wv & 3;            // 0..3

  const u32x4* abase = Ap + (size_t)mt * halvesK * 1024;
  const u32x4* bbase = Bp + (size_t)(e * NT + nt) * halvesK * 1024;

  auto stageA = [&](int Hs) {
    const u32x4* sa = abase + (size_t)Hs * 1024;
    const int s = Hs & 3;
    gld_lds16(sa + (wv * 2 + 0) * 64 + lane, &AsR[s * 1024 + (wv * 2 + 0) * 64]);
    gld_lds16(sa + (wv * 2 + 1) * 64 + lane, &AsR[s * 1024 + (wv * 2 + 1) * 64]);
  };
  auto stageB = [&](int Hs) {
    const u32x4* sb = bbase + (size_t)Hs * 1024;
    const int s = Hs & 3;
    gld_lds16(sb + (wv * 2 + 0) * 64 + lane, &BsR[s * 1024 + (wv * 2 + 0) * 64]);
    gld_lds16(sb + (wv * 2 + 1) * 64 + lane, &BsR[s * 1024 + (wv * 2 + 1) * 64]);
  };

  f32x4 acc[8][4] = {};
  const int NH = halvesK;

  stageA(0); stageB(0); stageA(1); stageB(1); stageA(2); stageB(2);  // 12 in flight

  for (int H = 0; H < NH; ++H) {
    const int rem = NH - 1 - H;
    if (rem >= 2)      asm volatile("s_waitcnt vmcnt(8)" ::: "memory");
    else if (rem == 1) asm volatile("s_waitcnt vmcnt(4)" ::: "memory");
    else               asm volatile("s_waitcnt vmcnt(0)" ::: "memory");
    __builtin_amdgcn_sched_barrier(0);
    __builtin_amdgcn_s_barrier();     // slab H complete in all waves; H-1 readers done
    __builtin_amdgcn_sched_barrier(0);
    const u32x4* Ah = AsR + (H & 3) * 1024;
    const u32x4* Bh = BsR + (H & 3) * 1024;
    const bool st = (H + 3 < NH);
    // ---- phase 0: stage A of H+3, read b[0..3]+a[0..3], 16 MFMA
    if (st) stageA(H + 3);
    __builtin_amdgcn_sched_barrier(0);
    s16x8 a[4], b[4];
#pragma unroll
    for (int ni = 0; ni < 4; ++ni)
      b[ni] = __builtin_bit_cast(s16x8, Bh[(wn * 4 + ni) * 64 + lane]);
#pragma unroll
    for (int mi = 0; mi < 4; ++mi)
      a[mi] = __builtin_bit_cast(s16x8, Ah[(wm * 8 + mi) * 64 + lane]);
    __builtin_amdgcn_s_setprio(1);
#pragma unroll
    for (int mi = 0; mi < 4; ++mi)
#pragma unroll
      for (int ni = 0; ni < 4; ++ni)
        acc[mi][ni] = __builtin_amdgcn_mfma_f32_16x16x32_bf16(a[mi], b[ni], acc[mi][ni], 0, 0, 0);
    __builtin_amdgcn_s_setprio(0);
    __builtin_amdgcn_sched_barrier(0);
    // ---- phase 1: stage B of H+3, read a[4..7], 16 MFMA
    if (st) stageB(H + 3);
    __builtin_amdgcn_sched_barrier(0);
#pragma unroll
    for (int mi = 0; mi < 4; ++mi)
      a[mi] = __builtin_bit_cast(s16x8, Ah[(wm * 8 + 4 + mi) * 64 + lane]);
    __builtin_amdgcn_s_setprio(1);
#pragma unroll
    for (int mi = 0; mi < 4; ++mi)
#pragma unroll
      for (int ni = 0; ni < 4; ++ni)
        acc[4 + mi][ni] = __builtin_amdgcn_mfma_f32_16x16x32_bf16(a[mi], b[ni], acc[4 + mi][ni], 0, 0, 0);
    __builtin_amdgcn_s_setprio(0);
  }

  __syncthreads();                    // all reads done; LDS free for epilogue

  const int rbase = ((lane >> 4) << 2);
  const int c16 = lane & 15;
  if (MODE) {
    // ---- GELU+bias; scatter to image layout in LDS; write 4 GEMM2 A-tiles
    u16* cimg = (u16*)LB;
    float bv[4];
#pragma unroll
    for (int ni = 0; ni < 4; ++ni)
      bv[ni] = bias[(size_t)e * Nfull + nt * 256 + wn * 64 + ni * 16 + c16];
#pragma unroll
    for (int mi = 0; mi < 8; ++mi)
#pragma unroll
      for (int ni = 0; ni < 4; ++ni)
#pragma unroll
        for (int r = 0; r < 4; ++r) {
          const int row = wm * 128 + mi * 16 + rbase + r;
          const int col = wn * 64 + ni * 16 + c16;
          float v = acc[mi][ni][r] + bv[ni];
          v = 0.5f * v * (1.0f + erff(v * 0.70710678118654752f));
          const int k = col & 63;
          const int ent = (col >> 6) * 2048
                        + ((k >> 5) * 16 + (row >> 4)) * 64
                        + ((k >> 3) & 3) * 16 + (row & 15);
          cimg[ent * 8 + (k & 7)] = f2bf(v);
        }
    __syncthreads();
    u32x4* outp = (u32x4*)outv + ((size_t)mt * KT2 + nt * 4) * 2048;
#pragma unroll
    for (int c = 0; c < 16; ++c) {
      const int idx = c * 512 + tid;
      outp[idx] = LB[idx];
    }
  } else {
    // ---- bias + bf16 y via swizzled LDS (u16[256][256]) -> coalesced rows
    u16* cimg = (u16*)LB;
    float bv[4];
#pragma unroll
    for (int ni = 0; ni < 4; ++ni)
      bv[ni] = bias[(size_t)e * Nfull + nt * 256 + wn * 64 + ni * 16 + c16];
#pragma unroll
    for (int mi = 0; mi < 8; ++mi)
#pragma unroll
      for (int ni = 0; ni < 4; ++ni)
#pragma unroll
        for (int r = 0; r < 4; ++r) {
          const int row = wm * 128 + mi * 16 + rbase + r;
          const int col = wn * 64 + ni * 16 + c16;
          const int ch = col >> 3;
          cimg[row * 256 + ((ch ^ (row & 31)) << 3) + (col & 7)] = f2bf(acc[mi][ni][r] + bv[ni]);
        }
    __syncthreads();
    u16* o = (u16*)outv;
#pragma unroll
    for (int c = 0; c < 16; ++c) {
      const int cid = c * 512 + tid;
      const int row = cid >> 5, ch = cid & 31;
      *(u32x4*)&o[(size_t)(mt * BM + row) * DMODEL + nt * 256 + ch * 8]
          = LB[row * 32 + (ch ^ (row & 31))];
    }
  }
}

// ---------------- combine (top-2 weighted) + residual + LayerNorm ----------------
__global__ void k_combine_ln(const float* __restrict__ x, const u16* __restrict__ y,
                             const int* __restrict__ token_slot, const float* __restrict__ top_w,
                             const float* __restrict__ gamma, const float* __restrict__ beta,
                             float* __restrict__ out) {
  int t = blockIdx.x, tid = threadIdx.x;
  int s0 = token_slot[2 * t], s1 = token_slot[2 * t + 1];
  float w0 = top_w[2 * t], w1 = top_w[2 * t + 1];
  float4 xv = ((const float4*)(x + (size_t)t * DMODEL))[tid];
  uint2 a = ((const uint2*)(y + (size_t)s0 * DMODEL))[tid];
  uint2 b = ((const uint2*)(y + (size_t)s1 * DMODEL))[tid];
  float r0 = xv.x + w0 * bf2f(a.x & 0xffffu) + w1 * bf2f(b.x & 0xffffu);
  float r1 = xv.y + w0 * bf2f(a.x >> 16)     + w1 * bf2f(b.x >> 16);
  float r2 = xv.z + w0 * bf2f(a.y & 0xffffu) + w1 * bf2f(b.y & 0xffffu);
  float r3 = xv.w + w0 * bf2f(a.y >> 16)     + w1 * bf2f(b.y >> 16);
  float s  = r0 + r1 + r2 + r3;
  float sq = r0 * r0 + r1 * r1 + r2 * r2 + r3 * r3;
#pragma unroll
  for (int off = 32; off; off >>= 1) { s += __shfl_down(s, off); sq += __shfl_down(sq, off); }
  __shared__ float rs[4], rq[4];
  __shared__ float mu_s, rsig_s;
  int w = tid >> 6;
  if ((tid & 63) == 0) { rs[w] = s; rq[w] = sq; }
  __syncthreads();
  if (tid == 0) {
    float S = rs[0] + rs[1] + rs[2] + rs[3];
    float Q = rq[0] + rq[1] + rq[2] + rq[3];
    float mu  = S * (1.0f / DMODEL);
    float var = Q * (1.0f / DMODEL) - mu * mu;
    mu_s = mu; rsig_s = rsqrtf(var + 1e-5f);
  }
  __syncthreads();
  float mu = mu_s, rsig = rsig_s;
  float4 gv = ((const float4*)gamma)[tid];
  float4 bv = ((const float4*)beta)[tid];
  float4 o;
  o.x = (r0 - mu) * rsig * gv.x + bv.x;
  o.y = (r1 - mu) * rsig * gv.y + bv.y;
  o.z = (r2 - mu) * rsig * gv.z + bv.z;
  o.w = (r3 - mu) * rsig * gv.w + bv.w;
  ((float4*)(out + (size_t)t * DMODEL))[tid] = o;
}

// ---------------- launch ----------------
extern "C" void kernel_launch(void* const* d_in, const int* in_sizes, int n_in,
                              void* d_out, int out_size, void* d_ws, size_t ws_size,
                              hipStream_t stream) {
  const float* x     = (const float*)d_in[0];
  const float* Wg    = (const float*)d_in[1];
  const float* bg    = (const float*)d_in[2];
  const float* W1    = (const float*)d_in[3];
  const float* b1    = (const float*)d_in[4];
  const float* W2    = (const float*)d_in[5];
  const float* b2    = (const float*)d_in[6];
  const float* gamma = (const float*)d_in[7];
  const float* beta  = (const float*)d_in[8];
  float* out = (float*)d_out;

  // ws ~225.6MiB: [Ap1 19.5 | Bp1 64][Bp2 64][hImg 78][meta]; yb aliases Ap1
  char* ws = (char*)d_ws;
  const size_t szAp1 = (size_t)MAX_MT * KT1 * 2048 * 16;         // 19.5 MiB
  const size_t szBp  = (size_t)NEXP * DMODEL * HFF * 2;          // 64 MiB
  u32x4* Ap1  = (u32x4*)ws;
  u16*   yb   = (u16*)ws;                                        // alias (post-GEMM1)
  u32x4* Bp1  = (u32x4*)(ws + szAp1);
  u32x4* Bp2  = (u32x4*)(ws + szAp1 + szBp);
  char* p = ws + szAp1 + 2 * szBp;
  u16*   hImg = (u16*)p;  p += (size_t)MAX_MT * KT2 * 2048 * 16; // 78 MiB
  int*   meta = (int*)p;
  int*   counts      = meta;
  int*   cursor      = counts + 8;
  int*   tok_of_slot = cursor + 8;
  int*   mtile_e     = tok_of_slot + MAX_MT * BM;
  int*   token_slot  = mtile_e + MT_PAD;
  int*   top_idx     = token_slot + 2 * NTOK;
  float* top_w       = (float*)(top_idx + 2 * NTOK);
  (void)ws_size; (void)in_sizes; (void)n_in; (void)out_size;

  hipMemsetAsync(meta, 0, (size_t)(16 + MAX_MT * BM) * 4, stream);

  k_gating<<<NTOK, 256, 0, stream>>>(x, Wg, bg, top_idx, top_w, counts);
  k_scatter<<<NTOK / 256, 256, 0, stream>>>(counts, mtile_e, cursor, top_idx,
                                            tok_of_slot, token_slot);

  // prep: preW1 (2048) + arrange_a (624) = 2672 blocks
  k_prep<<<2048 + MAX_MT * KT1, 256, 0, stream>>>(W1, Bp1, x, tok_of_slot, mtile_e, Ap1);

  // GEMM1 (640 blocks) + preW2 backfill (2048 blocks); GELU; h -> GEMM2 A-images
  k_gemm<1><<<NWG1 + 2048, 512, 0, stream>>>(
      Ap1, 2 * KT1, Bp1, b1, HFF, HFF / 256, mtile_e, (void*)hImg, W2, Bp2, NWG1);

  // GEMM2 (160 blocks); bias + bf16 y (swizzled epilogue)
  k_gemm<0><<<NWG2, 512, 0, stream>>>(
      (const u32x4*)hImg, 2 * KT2, Bp2, b2, DMODEL, DMODEL / 256, mtile_e,
      (void*)yb, nullptr, nullptr, NWG2);

  k_combine_ln<<<NTOK, 256, 0, stream>>>(x, yb, token_slot, top_w, gamma, beta, out);
}